// Round 2
// baseline (419.633 us; speedup 1.0000x reference)
//
#include <hip/hip_runtime.h>
#include <stdint.h>

#define DIN   63
#define BATCH 256
#define H1    256
#define H2    128
#define NEG   0.1f
#define EPSB  1e-5f

typedef _Float16 half2_t __attribute__((ext_vector_type(2)));
typedef _Float16 half8_t __attribute__((ext_vector_type(8)));
typedef float   float4_t __attribute__((ext_vector_type(4)));

#define V12_STRIDE 66      // halves per b-row: 64 j + 2 pad (conflict-free frag reads)
#define WT_STRIDE  72      // halves per n-row: 64 k + 8 pad (16B-aligned k-runs)
#define WT_BUF     (32 * WT_STRIDE)

union AFrag { half8_t v; half2_t h2[4]; };

static __device__ inline half2_t pack_f16(float a, float b) {
    half2_t h; h.x = (_Float16)a; h.y = (_Float16)b; return h;
}

// C[b,h] partial for one i-slab: A = x (on-the-fly, M=256), B = W1 slab (N=32 cols)
__global__ __launch_bounds__(256, 2)
void gemm1_kernel(const float* __restrict__ vec1, const float* __restrict__ vec2,
                  const float* __restrict__ vec3, const float* __restrict__ W1,
                  float* __restrict__ partial)
{
    const int nt    = blockIdx.x;          // 0..7   -> n0 = nt*32
    const int islab = blockIdx.y;          // 0..63  -> i
    const int n0    = nt * 32;
    const int tid   = threadIdx.x;
    const int lane  = tid & 63;
    const int wm    = tid >> 6;            // wave id -> M quarter (rows wm*64..wm*64+63)
    const int m16   = lane & 15;
    const int quad  = lane >> 4;

    __shared__ __align__(16) _Float16 v12all[BATCH * V12_STRIDE];
    __shared__ __align__(16) _Float16 Wt[2 * WT_BUF];

    // ---- one-time: v12all[b][j] = v1e[b,islab] * v2e[b,j]   (fp16, RTE)
    {
        const int b = tid;
        const float v1v = (islab < DIN) ? vec1[b * DIN + islab] : 1.0f;
        #pragma unroll
        for (int jp = 0; jp < 32; ++jp) {
            const int j0 = 2 * jp;
            const float a0 = v1v * ((j0     < DIN) ? vec2[b * DIN + j0    ] : 1.0f);
            const float a1 = v1v * ((j0 + 1 < DIN) ? vec2[b * DIN + j0 + 1] : 1.0f);
            *reinterpret_cast<half2_t*>(&v12all[b * V12_STRIDE + j0]) = pack_f16(a0, a1);
        }
    }

    // ---- one-time: v3 in registers, laid out exactly as MFMA A-frag k-runs
    half2_t v3h[4][2][4];   // [Mt][kk(K32 half)][half2 pair]
    #pragma unroll
    for (int Mt = 0; Mt < 4; ++Mt) {
        const int b = wm * 64 + Mt * 16 + m16;
        #pragma unroll
        for (int kk = 0; kk < 2; ++kk) {
            const int kb = kk * 32 + quad * 8;
            float v[8];
            #pragma unroll
            for (int t = 0; t < 8; ++t) {
                const int k = kb + t;
                v[t] = (k < DIN) ? vec3[b * DIN + k] : 1.0f;
            }
            #pragma unroll
            for (int s = 0; s < 4; ++s)
                v3h[Mt][kk][s] = pack_f16(v[2 * s], v[2 * s + 1]);
        }
    }

    // ---- W staging mapping: thread -> k-pair (2kp,2kp+1) x 4 n's
    const int kp  = tid & 31;
    const int nch = tid >> 5;              // 0..7 -> n = nch*4 + s

    float4_t sa, sb;                        // rows k=2kp and k=2kp+1, 4 cols each
    {   // load j = 0
        const size_t f = (size_t)islab * 4096 + 2 * kp;
        const float* p0 = W1 + f * H1 + n0 + nch * 4;
        sa = *reinterpret_cast<const float4_t*>(p0);
        sb = *reinterpret_cast<const float4_t*>(p0 + H1);
    }
    {   // write buf 0 (transposed, fp16): Wt[n][k] half2 = (k even, k odd)
        _Float16* wb = &Wt[0];
        #pragma unroll
        for (int s = 0; s < 4; ++s)
            *reinterpret_cast<half2_t*>(&wb[(nch * 4 + s) * WT_STRIDE + 2 * kp]) =
                pack_f16(sa[s], sb[s]);
    }
    __syncthreads();

    float4_t acc[4][2];
    #pragma unroll
    for (int Mt = 0; Mt < 4; ++Mt)
        #pragma unroll
        for (int Nt = 0; Nt < 2; ++Nt)
            acc[Mt][Nt] = (float4_t){0.f, 0.f, 0.f, 0.f};

    for (int j = 0; j < 64; ++j) {
        const int cur = j & 1;
        if (j + 1 < 64) {   // prefetch next j's W tile into regs (hidden under MFMA)
            const size_t f = (size_t)islab * 4096 + (size_t)(j + 1) * 64 + 2 * kp;
            const float* p0 = W1 + f * H1 + n0 + nch * 4;
            sa = *reinterpret_cast<const float4_t*>(p0);
            sb = *reinterpret_cast<const float4_t*>(p0 + H1);
        }

        const _Float16* wb = &Wt[cur * WT_BUF];
        half8_t bfrag[2][2];   // [kk][Nt]
        #pragma unroll
        for (int kk = 0; kk < 2; ++kk)
            #pragma unroll
            for (int Nt = 0; Nt < 2; ++Nt) {
                const int n = Nt * 16 + m16;
                bfrag[kk][Nt] = *reinterpret_cast<const half8_t*>(
                    &wb[n * WT_STRIDE + kk * 32 + quad * 8]);
            }

        #pragma unroll
        for (int Mt = 0; Mt < 4; ++Mt) {
            const int b = wm * 64 + Mt * 16 + m16;
            const _Float16 v12 = v12all[b * V12_STRIDE + j];
            half2_t vv; vv.x = v12; vv.y = v12;
            #pragma unroll
            for (int kk = 0; kk < 2; ++kk) {
                AFrag af;
                #pragma unroll
                for (int s = 0; s < 4; ++s) af.h2[s] = vv * v3h[Mt][kk][s];
                acc[Mt][0] = __builtin_amdgcn_mfma_f32_16x16x32_f16(af.v, bfrag[kk][0], acc[Mt][0], 0, 0, 0);
                acc[Mt][1] = __builtin_amdgcn_mfma_f32_16x16x32_f16(af.v, bfrag[kk][1], acc[Mt][1], 0, 0, 0);
            }
        }
        __syncthreads();                   // all reads of buf `cur` done
        if (j + 1 < 64) {
            _Float16* wb2 = &Wt[(cur ^ 1) * WT_BUF];
            #pragma unroll
            for (int s = 0; s < 4; ++s)
                *reinterpret_cast<half2_t*>(&wb2[(nch * 4 + s) * WT_STRIDE + 2 * kp]) =
                    pack_f16(sa[s], sb[s]);
        }
        __syncthreads();                   // buf `cur^1` ready for next iter
    }

    // ---- store partial tile: D layout n=lane&15, m=quad*4+r (verified gfx950 C/D map)
    #pragma unroll
    for (int Mt = 0; Mt < 4; ++Mt) {
        const int brow = wm * 64 + Mt * 16 + quad * 4;
        #pragma unroll
        for (int Nt = 0; Nt < 2; ++Nt) {
            const int n = n0 + Nt * 16 + m16;
            #pragma unroll
            for (int r = 0; r < 4; ++r)
                partial[(size_t)islab * (BATCH * H1) + (size_t)(brow + r) * H1 + n] = acc[Mt][Nt][r];
        }
    }
}

// reduce 64 partial slabs -> leaky+BN1 -> layer2 -> leaky+BN2 -> dot with Wc
__global__ __launch_bounds__(256)
void tail_kernel(const float* __restrict__ partial,
                 const float* __restrict__ b1, const float* __restrict__ g1,
                 const float* __restrict__ be1, const float* __restrict__ rm1,
                 const float* __restrict__ rv1,
                 const float* __restrict__ W2, const float* __restrict__ b2,
                 const float* __restrict__ g2, const float* __restrict__ be2,
                 const float* __restrict__ rm2, const float* __restrict__ rv2,
                 const float* __restrict__ Wc, const float* __restrict__ bc,
                 float* __restrict__ out)
{
    const int b = blockIdx.x;
    const int t = threadIdx.x;
    __shared__ float h1row[H1];
    __shared__ float ph[2][H2];
    __shared__ float h2row[H2];

    float s = 0.0f;
    const float* p = partial + (size_t)b * H1 + t;
    #pragma unroll 8
    for (int i = 0; i < 64; ++i) s += p[(size_t)i * (BATCH * H1)];
    s += b1[t];
    s = (s >= 0.0f) ? s : NEG * s;
    s = (s - rm1[t]) * rsqrtf(rv1[t] + EPSB) * g1[t] + be1[t];
    h1row[t] = s;
    __syncthreads();

    {   // layer 2: two half-K partial sums per output column
        const int n    = t & 127;
        const int half = t >> 7;
        const int h0   = half * 128;
        float acc = 0.0f;
        #pragma unroll 4
        for (int h = 0; h < 128; ++h)
            acc += h1row[h0 + h] * W2[(size_t)(h0 + h) * H2 + n];
        ph[half][n] = acc;
    }
    __syncthreads();
    if (t < H2) {
        float acc = ph[0][t] + ph[1][t] + b2[t];
        acc = (acc >= 0.0f) ? acc : NEG * acc;
        acc = (acc - rm2[t]) * rsqrtf(rv2[t] + EPSB) * g2[t] + be2[t];
        h2row[t] = acc;
    }
    __syncthreads();
    if (t < 64) {
        float v = h2row[t] * Wc[t] + h2row[t + 64] * Wc[t + 64];
        #pragma unroll
        for (int off = 32; off > 0; off >>= 1) v += __shfl_down(v, off);
        if (t == 0) out[b] = v + bc[0];
    }
}

extern "C" void kernel_launch(void* const* d_in, const int* in_sizes, int n_in,
                              void* d_out, int out_size, void* d_ws, size_t ws_size,
                              hipStream_t stream)
{
    const float* vec1 = (const float*)d_in[0];
    const float* vec2 = (const float*)d_in[1];
    const float* vec3 = (const float*)d_in[2];
    const float* W1   = (const float*)d_in[3];
    const float* b1   = (const float*)d_in[4];
    const float* g1   = (const float*)d_in[5];
    const float* be1  = (const float*)d_in[6];
    const float* rm1  = (const float*)d_in[7];
    const float* rv1  = (const float*)d_in[8];
    const float* W2   = (const float*)d_in[9];
    const float* b2   = (const float*)d_in[10];
    const float* g2   = (const float*)d_in[11];
    const float* be2  = (const float*)d_in[12];
    const float* rm2  = (const float*)d_in[13];
    const float* rv2  = (const float*)d_in[14];
    const float* Wc   = (const float*)d_in[15];
    const float* bc   = (const float*)d_in[16];

    float* partial = (float*)d_ws;   // 64 * 256 * 256 * 4 B = 16.8 MB scratch

    gemm1_kernel<<<dim3(8, 64), 256, 0, stream>>>(vec1, vec2, vec3, W1, partial);
    tail_kernel<<<256, 256, 0, stream>>>(partial, b1, g1, be1, rm1, rv1,
                                         W2, b2, g2, be2, rm2, rv2, Wc, bc,
                                         (float*)d_out);
}